// Round 1
// baseline (2442.105 us; speedup 1.0000x reference)
//
#include <hip/hip_runtime.h>

// LSTM: B=128, T=1024, H=128, D=64, L=3. PyTorch gate order (i,f,g,o).
// Plan: per layer, parallel bf16-MFMA GEMM for xg = y@Wih^T + (bih+bhh),
// then a persistent-weight recurrence kernel (Whh in VGPR B-frags, h in LDS,
// xg staged via global_load_lds, fp32 cell state + gate math).

#define BATCH 128
#define TT    1024
#define HH    128
#define DD    64
#define G4    512
#define NB    4              // batches per recurrence workgroup
#define XSTR  1040           // LDS row stride (bytes) for staged xg row (1024 + 16 pad)
#define HSTR  272            // LDS row stride (bytes) for h rows (256 + 16 pad)

typedef __attribute__((ext_vector_type(4))) float f32x4;
typedef __attribute__((ext_vector_type(8))) short bf16x8;
typedef __attribute__((ext_vector_type(4))) short bf16x4;

__device__ inline unsigned short f2bf(float f) {           // round-to-nearest-even
  unsigned u = __builtin_bit_cast(unsigned, f);
  u += 0x7FFFu + ((u >> 16) & 1u);
  return (unsigned short)(u >> 16);
}
__device__ inline float bf2f(unsigned short s) {
  return __builtin_bit_cast(float, (unsigned)s << 16);
}
__device__ inline float fast_sig(float x) {                // 1/(1+e^-x), ~1ulp exp/rcp
  return __builtin_amdgcn_rcpf(1.f + exp2f(-1.442695041f * x));
}
__device__ inline float fast_tanh(float x) {               // 2*sig(2x)-1
  return 2.f * __builtin_amdgcn_rcpf(1.f + exp2f(-2.885390082f * x)) - 1.f;
}
__device__ inline bf16x8 pack8(f32x4 a, f32x4 b) {
  bf16x8 r;
  r[0]=(short)f2bf(a[0]); r[1]=(short)f2bf(a[1]); r[2]=(short)f2bf(a[2]); r[3]=(short)f2bf(a[3]);
  r[4]=(short)f2bf(b[0]); r[5]=(short)f2bf(b[1]); r[6]=(short)f2bf(b[2]); r[7]=(short)f2bf(b[3]);
  return r;
}
__device__ inline void load_lds16(const void* g, void* l) {
  __builtin_amdgcn_global_load_lds(
      (const __attribute__((address_space(1))) unsigned int*)g,
      (__attribute__((address_space(3))) unsigned int*)l, 16, 0, 0);
}

// ---------------- fp32 -> bf16 convert ----------------
__global__ void cvt_bf16(const float* __restrict__ x, unsigned short* __restrict__ xb, int n) {
  int i = (blockIdx.x * 256 + threadIdx.x) * 4;
  if (i < n) {
    f32x4 v = *(const f32x4*)(x + i);
    bf16x4 s;
    s[0]=(short)f2bf(v[0]); s[1]=(short)f2bf(v[1]); s[2]=(short)f2bf(v[2]); s[3]=(short)f2bf(v[3]);
    *(bf16x4*)(xb + i) = s;
  }
}

// ---------------- xg GEMM: [BT x K] @ [K x 512] + bias -> bf16 ----------------
// WG=256 (4 waves), M-tile 64, full N=512. Wave w owns n in [w*128,(w+1)*128).
template<int K>
__global__ __launch_bounds__(256, 2) void xg_gemm(
    const unsigned short* __restrict__ A,     // [BT][K] bf16
    const float* __restrict__ Wih,            // [512][K] fp32
    const float* __restrict__ bih, const float* __restrict__ bhh,
    unsigned short* __restrict__ xg)          // [BT][512] bf16
{
  constexpr int KC = K / 32;
  constexpr int ASTR = K * 2 + 16;
  __shared__ char alds[64 * ASTR];
  int tid = threadIdx.x, wave = tid >> 6, lane = tid & 63, quad = lane >> 4, l15 = lane & 15;
  size_t M0 = (size_t)blockIdx.x * 64;

  // stage A tile (64 x K) to padded LDS
#pragma unroll
  for (int v = 0; v < (64 * K) / (256 * 8); ++v) {
    int e = (tid + v * 256) * 8;
    int row = e / K, col = e % K;
    bf16x8 d = *(const bf16x8*)(A + M0 * K + e);
    *(bf16x8*)(alds + row * ASTR + col * 2) = d;
  }
  __syncthreads();

  bf16x8 af[4][KC];
#pragma unroll
  for (int mt = 0; mt < 4; ++mt)
#pragma unroll
    for (int kc = 0; kc < KC; ++kc)
      af[mt][kc] = *(const bf16x8*)(alds + (mt * 16 + l15) * ASTR + quad * 16 + kc * 64);

#pragma unroll
  for (int half = 0; half < 2; ++half) {
    f32x4 acc[4][4];
#pragma unroll
    for (int a = 0; a < 4; ++a)
#pragma unroll
      for (int b = 0; b < 4; ++b) acc[a][b] = (f32x4){0.f, 0.f, 0.f, 0.f};

#pragma unroll
    for (int nt4 = 0; nt4 < 4; ++nt4) {
      int n = wave * 128 + (half * 4 + nt4) * 16 + l15;
      bf16x8 bfr[KC];
#pragma unroll
      for (int kc = 0; kc < KC; ++kc) {
        const float* p = Wih + (size_t)n * K + quad * 8 + kc * 32;
        bfr[kc] = pack8(*(const f32x4*)p, *(const f32x4*)(p + 4));
      }
#pragma unroll
      for (int kc = 0; kc < KC; ++kc)
#pragma unroll
        for (int mt = 0; mt < 4; ++mt)
          acc[nt4][mt] = __builtin_amdgcn_mfma_f32_16x16x32_bf16(af[mt][kc], bfr[kc], acc[nt4][mt], 0, 0, 0);
    }
#pragma unroll
    for (int nt4 = 0; nt4 < 4; ++nt4) {
      int n = wave * 128 + (half * 4 + nt4) * 16 + l15;
      float bias = bih[n] + bhh[n];
#pragma unroll
      for (int mt = 0; mt < 4; ++mt)
#pragma unroll
        for (int r = 0; r < 4; ++r)
          xg[(M0 + mt * 16 + quad * 4 + r) * (size_t)G4 + n] = f2bf(acc[nt4][mt][r] + bias);
    }
  }
}

// ---------------- recurrence: one layer, NB batches per WG ----------------
// WG=512 (8 waves). Wave w owns hidden units j in [w*16,(w+1)*16) -> gate rows
// {j, 128+j, 256+j, 384+j}. Real batches at MFMA C rows m = quad*4 (reg 0).
__global__ __launch_bounds__(512, 2) void lstm_rec(
    const unsigned short* __restrict__ xg_in, // [B][T][512] bf16
    const float* __restrict__ Whh,            // [512][128]
    const float* __restrict__ h0,             // [B][128] (layer slice)
    const float* __restrict__ c0,
    float* __restrict__ hN, float* __restrict__ cN,
    unsigned short* __restrict__ y_out,       // [B][T][128] bf16 (layers 0,1)
    float* __restrict__ outp,                 // [B][T] (layer 2)
    const float* __restrict__ Wout, const float* __restrict__ boutp,
    int is_last)
{
  __shared__ char xls[2 * 16 * XSTR];   // staged xg, double buffered
  __shared__ char hls[2 * 16 * HSTR];   // h (bf16), double buffered
  int tid = threadIdx.x, wave = tid >> 6, lane = tid & 63, quad = lane >> 4, l15 = lane & 15;
  int bg0 = blockIdx.x * NB;
  int j = wave * 16 + l15;

  // Whh B-fragments -> registers (64 VGPR): B[k][n] = Whh[n][k]
  bf16x8 bw[4][4];
#pragma unroll
  for (int q = 0; q < 4; ++q) {
    int n = q * 128 + wave * 16 + l15;
#pragma unroll
    for (int kc = 0; kc < 4; ++kc) {
      const float* p = Whh + (size_t)n * HH + quad * 8 + kc * 32;
      bw[q][kc] = pack8(*(const f32x4*)p, *(const f32x4*)(p + 4));
    }
  }

  // zero both h buffers (pad rows must be 0 for MFMA A)
  {
    int* hi = (int*)hls;
    for (int o = tid; o < 2 * 16 * HSTR / 4; o += 512) hi[o] = 0;
  }
  __syncthreads();
  // h0 -> buffer 0 (real rows m = bl*4)
  if (tid < 32 * NB) {
    int bl = tid >> 5, j4 = (tid & 31) * 4, m = bl * 4;
    f32x4 v = *(const f32x4*)(h0 + (size_t)(bg0 + bl) * HH + j4);
    bf16x4 s;
    s[0]=(short)f2bf(v[0]); s[1]=(short)f2bf(v[1]); s[2]=(short)f2bf(v[2]); s[3]=(short)f2bf(v[3]);
    *(bf16x4*)(hls + m * HSTR + j4 * 2) = s;
  }
  float cc = c0[(size_t)(bg0 + quad) * HH + j];

  float w0=0.f, w1=0.f, w2=0.f, w3=0.f, ob=0.f;
  if (is_last && tid < 32 * NB) {
    int j4 = (tid & 31) * 4;
    w0 = Wout[j4]; w1 = Wout[j4+1]; w2 = Wout[j4+2]; w3 = Wout[j4+3];
    ob = boutp[0];
  }

  auto stage = [&](int t, int sel) {
    if (wave < NB) {
      const char* g = (const char*)(xg_in + ((size_t)(bg0 + wave) * TT + t) * G4) + lane * 16;
      char* l = xls + sel * (16 * XSTR) + (wave * 4) * XSTR + lane * 16;
      load_lds16(g, l);
    }
  };
  auto proj = [&](int tt, int sel) {
    int bl = tid >> 5, j4 = (tid & 31) * 4, m = bl * 4;
    const char* hb = hls + sel * (16 * HSTR);
    bf16x4 hv = *(const bf16x4*)(hb + m * HSTR + j4 * 2);
    float s = bf2f((unsigned short)hv[0]) * w0 + bf2f((unsigned short)hv[1]) * w1
            + bf2f((unsigned short)hv[2]) * w2 + bf2f((unsigned short)hv[3]) * w3;
#pragma unroll
    for (int off = 16; off > 0; off >>= 1) s += __shfl_xor(s, off, 32);
    if ((tid & 31) == 0) outp[(size_t)(bg0 + bl) * TT + tt] = fmaxf(s + ob, 0.f);
  };

  stage(0, 0);
  __syncthreads();

  for (int t = 0; t < TT; ++t) {
    int cur = t & 1, nxt = cur ^ 1;
    if (t + 1 < TT) stage(t + 1, nxt);               // async prefetch, drained by barrier
    if (is_last && t > 0 && tid < 32 * NB) proj(t - 1, cur);

    // A-frags: h rows (m = l15) from current buffer
    const char* hb = hls + cur * (16 * HSTR) + l15 * HSTR + quad * 16;
    bf16x8 a0 = *(const bf16x8*)(hb + 0);
    bf16x8 a1 = *(const bf16x8*)(hb + 64);
    bf16x8 a2 = *(const bf16x8*)(hb + 128);
    bf16x8 a3 = *(const bf16x8*)(hb + 192);

    const char* xb = xls + cur * (16 * XSTR);
    f32x4 acc[4];
#pragma unroll
    for (int q = 0; q < 4; ++q) {
      int n = q * 128 + wave * 16 + l15;
      f32x4 t0 = {bf2f(*(const unsigned short*)(xb + (quad * 4) * XSTR + n * 2)), 0.f, 0.f, 0.f};
      acc[q] = t0;
    }
#pragma unroll
    for (int q = 0; q < 4; ++q) {
      acc[q] = __builtin_amdgcn_mfma_f32_16x16x32_bf16(a0, bw[q][0], acc[q], 0, 0, 0);
      acc[q] = __builtin_amdgcn_mfma_f32_16x16x32_bf16(a1, bw[q][1], acc[q], 0, 0, 0);
      acc[q] = __builtin_amdgcn_mfma_f32_16x16x32_bf16(a2, bw[q][2], acc[q], 0, 0, 0);
      acc[q] = __builtin_amdgcn_mfma_f32_16x16x32_bf16(a3, bw[q][3], acc[q], 0, 0, 0);
    }

    // gates (reg 0 = real batch m = quad*4 -> b = bg0+quad), fp32 state
    float gi = fast_sig(acc[0][0]);
    float gf = fast_sig(acc[1][0]);
    float gg = fast_tanh(acc[2][0]);
    float go = fast_sig(acc[3][0]);
    cc = gf * cc + gi * gg;
    float hv = go * fast_tanh(cc);
    char* hn = hls + nxt * (16 * HSTR);
    *(unsigned short*)(hn + (quad * 4) * HSTR + j * 2) = f2bf(hv);
    if (!is_last) y_out[((size_t)(bg0 + quad) * TT + t) * HH + j] = f2bf(hv);
    if (t == TT - 1) {
      hN[(size_t)(bg0 + quad) * HH + j] = hv;
      cN[(size_t)(bg0 + quad) * HH + j] = cc;
    }
    __syncthreads();
  }
  if (is_last && tid < 32 * NB) proj(TT - 1, 0);   // h_{1023} lives in buffer 0
}

// ---------------- launch ----------------
extern "C" void kernel_launch(void* const* d_in, const int* in_sizes, int n_in,
                              void* d_out, int out_size, void* d_ws, size_t ws_size,
                              hipStream_t stream) {
  const float* x  = (const float*)d_in[0];
  const float* h0 = (const float*)d_in[1];
  const float* c0 = (const float*)d_in[2];
  const float* Wih[3] = {(const float*)d_in[3], (const float*)d_in[7],  (const float*)d_in[11]};
  const float* Whh[3] = {(const float*)d_in[4], (const float*)d_in[8],  (const float*)d_in[12]};
  const float* bih[3] = {(const float*)d_in[5], (const float*)d_in[9],  (const float*)d_in[13]};
  const float* bhh[3] = {(const float*)d_in[6], (const float*)d_in[10], (const float*)d_in[14]};
  const float* Wout = (const float*)d_in[15];
  const float* bout = (const float*)d_in[16];

  float* outp = (float*)d_out;                 // [B][T]
  float* hN = outp + BATCH * TT;               // [L][B][H]
  float* cN = hN + 3 * BATCH * HH;

  char* ws = (char*)d_ws;
  unsigned short* x_bf = (unsigned short*)ws;                      // 16 MB
  unsigned short* y_bf = (unsigned short*)(ws + (size_t)16777216); // 32 MB
  unsigned short* xg   = (unsigned short*)(ws + (size_t)50331648); // 128 MB

  cvt_bf16<<<8192, 256, 0, stream>>>(x, x_bf, BATCH * TT * DD);

  xg_gemm<64><<<2048, 256, 0, stream>>>(x_bf, Wih[0], bih[0], bhh[0], xg);
  lstm_rec<<<BATCH / NB, 512, 0, stream>>>(xg, Whh[0], h0, c0,
                                           hN, cN, y_bf, nullptr, Wout, bout, 0);

  xg_gemm<128><<<2048, 256, 0, stream>>>(y_bf, Wih[1], bih[1], bhh[1], xg);
  lstm_rec<<<BATCH / NB, 512, 0, stream>>>(xg, Whh[1], h0 + BATCH * HH, c0 + BATCH * HH,
                                           hN + BATCH * HH, cN + BATCH * HH, y_bf, nullptr, Wout, bout, 0);

  xg_gemm<128><<<2048, 256, 0, stream>>>(y_bf, Wih[2], bih[2], bhh[2], xg);
  lstm_rec<<<BATCH / NB, 512, 0, stream>>>(xg, Whh[2], h0 + 2 * BATCH * HH, c0 + 2 * BATCH * HH,
                                           hN + 2 * BATCH * HH, cN + 2 * BATCH * HH, nullptr, outp, Wout, bout, 1);
}

// Round 2
// 1784.958 us; speedup vs baseline: 1.3682x; 1.3682x over previous
//
#include <hip/hip_runtime.h>

// LSTM B=128,T=1024,H=128,D=64,L=3. R1: register-prefetched xg (depth PD),
// lgkmcnt-only barrier (keeps vmem loads in flight across steps), h exchanged
// through LDS in A-fragment order (conflict-free ds_read_b128).

#define BATCH 128
#define TT    1024
#define HH    128
#define DD    64
#define NB    4        // batches per recurrence WG
#define PD    4        // xg register prefetch depth (steps)

typedef __attribute__((ext_vector_type(4))) float f32x4;
typedef __attribute__((ext_vector_type(8))) short bf16x8;
typedef __attribute__((ext_vector_type(4))) short bf16x4;

__device__ inline unsigned short f2bf(float f) {           // RNE
  unsigned u = __builtin_bit_cast(unsigned, f);
  u += 0x7FFFu + ((u >> 16) & 1u);
  return (unsigned short)(u >> 16);
}
__device__ inline float bf2f(unsigned short s) {
  return __builtin_bit_cast(float, (unsigned)s << 16);
}
__device__ inline float fsig(float x) {
  return __builtin_amdgcn_rcpf(1.f + __builtin_amdgcn_exp2f(-1.442695041f * x));
}
__device__ inline float ftanh(float x) {
  return 2.f * __builtin_amdgcn_rcpf(1.f + __builtin_amdgcn_exp2f(-2.885390082f * x)) - 1.f;
}
__device__ inline bf16x8 pack8(f32x4 a, f32x4 b) {
  bf16x8 r;
  r[0]=(short)f2bf(a[0]); r[1]=(short)f2bf(a[1]); r[2]=(short)f2bf(a[2]); r[3]=(short)f2bf(a[3]);
  r[4]=(short)f2bf(b[0]); r[5]=(short)f2bf(b[1]); r[6]=(short)f2bf(b[2]); r[7]=(short)f2bf(b[3]);
  return r;
}
// LDS-only barrier: does NOT drain vmcnt, so global-load prefetch stays in
// flight across steps (CK block_sync_lds pattern).
__device__ inline void bar_lds() {
  asm volatile("s_waitcnt lgkmcnt(0)\n\ts_barrier" ::: "memory");
}

// ---------------- fp32 -> bf16 convert ----------------
__global__ void cvt_bf16(const float* __restrict__ x, unsigned short* __restrict__ xb, int n) {
  int i = (blockIdx.x * 256 + threadIdx.x) * 4;
  if (i < n) {
    f32x4 v = *(const f32x4*)(x + i);
    bf16x4 s;
    s[0]=(short)f2bf(v[0]); s[1]=(short)f2bf(v[1]); s[2]=(short)f2bf(v[2]); s[3]=(short)f2bf(v[3]);
    *(bf16x4*)(xb + i) = s;
  }
}

// ---------------- xg GEMM: [BT x K] @ [K x 512] + bias -> bf16 ----------------
// Output layout PERMUTED: xg[row][j][q]  (row = b*T+t, j = hidden unit, q = gate)
// so the recurrence loads one 8B vector per thread per step.
// Wave w owns n-tiles {q*128 + w*32 + half*16 : q, half}; thread gets all 4 q's
// for its j and writes one bf16x4.
template<int K>
__global__ __launch_bounds__(256, 2) void xg_gemm(
    const unsigned short* __restrict__ A,     // [BT][K] bf16
    const float* __restrict__ Wih,            // [512][K] fp32
    const float* __restrict__ bih, const float* __restrict__ bhh,
    unsigned short* __restrict__ xg)          // [BT][128][4] bf16
{
  constexpr int KC = K / 32;
  constexpr int ASTR = K * 2 + 16;
  __shared__ char alds[64 * ASTR];
  int tid = threadIdx.x, wave = tid >> 6, lane = tid & 63, quad = lane >> 4, l15 = lane & 15;
  size_t M0 = (size_t)blockIdx.x * 64;

  // stage A tile (64 x K) to padded LDS
#pragma unroll
  for (int v = 0; v < (64 * K) / (256 * 8); ++v) {
    int e = (tid + v * 256) * 8;
    int row = e / K, col = e % K;
    bf16x8 d = *(const bf16x8*)(A + M0 * K + e);
    *(bf16x8*)(alds + row * ASTR + col * 2) = d;
  }
  __syncthreads();

  bf16x8 af[4][KC];
#pragma unroll
  for (int mt = 0; mt < 4; ++mt)
#pragma unroll
    for (int kc = 0; kc < KC; ++kc)
      af[mt][kc] = *(const bf16x8*)(alds + (mt * 16 + l15) * ASTR + quad * 16 + kc * 64);

#pragma unroll
  for (int half = 0; half < 2; ++half) {
    int j = wave * 32 + half * 16 + l15;
    f32x4 acc[4][4];                         // [q][mt]
#pragma unroll
    for (int q = 0; q < 4; ++q) {
      bf16x8 bfr[KC];
#pragma unroll
      for (int kc = 0; kc < KC; ++kc) {
        const float* p = Wih + (size_t)(q * 128 + j) * K + quad * 8 + kc * 32;
        bfr[kc] = pack8(*(const f32x4*)p, *(const f32x4*)(p + 4));
      }
#pragma unroll
      for (int mt = 0; mt < 4; ++mt) acc[q][mt] = (f32x4){0.f,0.f,0.f,0.f};
#pragma unroll
      for (int kc = 0; kc < KC; ++kc)
#pragma unroll
        for (int mt = 0; mt < 4; ++mt)
          acc[q][mt] = __builtin_amdgcn_mfma_f32_16x16x32_bf16(af[mt][kc], bfr[kc], acc[q][mt], 0, 0, 0);
    }
    float bs[4];
#pragma unroll
    for (int q = 0; q < 4; ++q) bs[q] = bih[q * 128 + j] + bhh[q * 128 + j];
#pragma unroll
    for (int mt = 0; mt < 4; ++mt)
#pragma unroll
      for (int r = 0; r < 4; ++r) {
        size_t row = M0 + mt * 16 + quad * 4 + r;
        bf16x4 o;
#pragma unroll
        for (int q = 0; q < 4; ++q) o[q] = (short)f2bf(acc[q][mt][r] + bs[q]);
        *(bf16x4*)(xg + row * 512 + j * 4) = o;
      }
  }
}

// ---------------- recurrence ----------------
// WG=512 (8 waves), NB=4 batches. Thread (wave,quad,l15) owns (b=bg0+quad,
// j=wave*16+l15); Whh B-frags persistent in VGPRs; h double-buffered in LDS in
// A-FRAGMENT ORDER: byte(kc,lane,e) = kc*1024 + lane*16 + e*2 with
// m=lane&15, k=(lane>>4)*8+kc*32+e. Readers: ds_read_b128 at lane*16 (conflict
// free). Garbage A rows (m != quad*4) only produce discarded C rows.
template<int IS_LAST>
__global__ __launch_bounds__(512, 2) void lstm_rec(
    const unsigned short* __restrict__ xg,    // [B][T][128][4] bf16
    const float* __restrict__ Whh,            // [512][128]
    const float* __restrict__ h0, const float* __restrict__ c0,
    float* __restrict__ hN, float* __restrict__ cN,
    unsigned short* __restrict__ y_out,       // [B][T][128] bf16 (layers 0,1)
    float* __restrict__ outp,                 // [B][T] (layer 2)
    const float* __restrict__ Wout, const float* __restrict__ boutp)
{
  __shared__ __align__(16) char hA[2][4096];
  int tid = threadIdx.x, wave = tid >> 6, lane = tid & 63, quad = lane >> 4, l15 = lane & 15;
  int bg0 = blockIdx.x * NB;
  int b = bg0 + quad;
  int j = wave * 16 + l15;

  // Whh B-frags -> 64 VGPR: tile n = q*128 + j, k = quad*8 + kc*32 + e
  bf16x8 bw[4][4];
#pragma unroll
  for (int q = 0; q < 4; ++q)
#pragma unroll
    for (int kc = 0; kc < 4; ++kc) {
      const float* p = Whh + (size_t)(q * 128 + j) * HH + quad * 8 + kc * 32;
      bw[q][kc] = pack8(*(const f32x4*)p, *(const f32x4*)(p + 4));
    }

  // write offset for h(m=quad*4, k=j) in A-frag order
  int lane_w = ((2 * wave + (l15 >> 3)) & 3) * 16 + quad * 4;
  int off_w = (wave >> 1) * 1024 + lane_w * 16 + (l15 & 7) * 2;

  *(unsigned short*)(hA[0] + off_w) = f2bf(h0[(size_t)b * HH + j]);
  float cc = c0[(size_t)b * HH + j];

  // projection setup (layer 2): tid<128, 32 threads per batch
  f32x4 wv = {0.f,0.f,0.f,0.f};
  float ob = 0.f;
  int prd_off = 0, pbl = 0;
  if (IS_LAST && tid < 128) {
    pbl = tid >> 5;
    int j4 = (tid & 31) * 4;
    wv = *(const f32x4*)(Wout + j4);
    ob = boutp[0];
    int lane_p = ((j4 >> 3) & 3) * 16 + pbl * 4;
    prd_off = (j4 >> 5) * 1024 + lane_p * 16 + (j4 & 7) * 2;
  }

  // xg register prefetch, depth PD
  const unsigned short* xp = xg + (size_t)b * (TT * 512) + j * 4;
  bf16x4 xq[PD];
#pragma unroll
  for (int u = 0; u < PD; ++u) xq[u] = *(const bf16x4*)(xp + u * 512);

  bar_lds();

  const f32x4 z4 = {0.f, 0.f, 0.f, 0.f};

  for (int t4 = 0; t4 < TT / PD; ++t4) {
#pragma unroll
    for (int u = 0; u < PD; ++u) {
      int t = t4 * PD + u;
      char* cur = hA[u & 1];
      char* nxt = hA[(u & 1) ^ 1];

      // consume prefetched xg, then reissue for t+PD
      float xv0 = bf2f((unsigned short)xq[u][0]);
      float xv1 = bf2f((unsigned short)xq[u][1]);
      float xv2 = bf2f((unsigned short)xq[u][2]);
      float xv3 = bf2f((unsigned short)xq[u][3]);
      if (t4 < TT / PD - 1) xq[u] = *(const bf16x4*)(xp + (size_t)(t + PD) * 512);

      // h A-frags: contiguous lane*16 reads
      bf16x8 a0 = *(const bf16x8*)(cur + lane * 16);
      bf16x8 a1 = *(const bf16x8*)(cur + 1024 + lane * 16);
      bf16x8 a2 = *(const bf16x8*)(cur + 2048 + lane * 16);
      bf16x8 a3 = *(const bf16x8*)(cur + 3072 + lane * 16);

      f32x4 ac[4];
#pragma unroll
      for (int q = 0; q < 4; ++q) ac[q] = __builtin_amdgcn_mfma_f32_16x16x32_bf16(a0, bw[q][0], z4, 0, 0, 0);
#pragma unroll
      for (int q = 0; q < 4; ++q) ac[q] = __builtin_amdgcn_mfma_f32_16x16x32_bf16(a1, bw[q][1], ac[q], 0, 0, 0);
#pragma unroll
      for (int q = 0; q < 4; ++q) ac[q] = __builtin_amdgcn_mfma_f32_16x16x32_bf16(a2, bw[q][2], ac[q], 0, 0, 0);
#pragma unroll
      for (int q = 0; q < 4; ++q) ac[q] = __builtin_amdgcn_mfma_f32_16x16x32_bf16(a3, bw[q][3], ac[q], 0, 0, 0);

      // overlapped projection of h_{t-1} (lives in cur) for layer 2
      if (IS_LAST && t > 0 && tid < 128) {
        bf16x4 hv4 = *(const bf16x4*)(cur + prd_off);
        float s = bf2f((unsigned short)hv4[0]) * wv[0] + bf2f((unsigned short)hv4[1]) * wv[1]
                + bf2f((unsigned short)hv4[2]) * wv[2] + bf2f((unsigned short)hv4[3]) * wv[3];
#pragma unroll
        for (int off = 16; off > 0; off >>= 1) s += __shfl_xor(s, off, 32);
        if ((tid & 31) == 0) outp[(size_t)(bg0 + pbl) * TT + (t - 1)] = fmaxf(s + ob, 0.f);
      }

      // gates + state (fp32)
      float gi = fsig(ac[0][0] + xv0);
      float gf = fsig(ac[1][0] + xv1);
      float gg = ftanh(ac[2][0] + xv2);
      float go = fsig(ac[3][0] + xv3);
      cc = gf * cc + gi * gg;
      float hv = go * ftanh(cc);
      *(unsigned short*)(nxt + off_w) = f2bf(hv);
      if (!IS_LAST) y_out[((size_t)b * TT + t) * HH + j] = f2bf(hv);
      if (t == TT - 1) {
        hN[(size_t)b * HH + j] = hv;
        cN[(size_t)b * HH + j] = cc;
      }
      bar_lds();
    }
  }

  if (IS_LAST && tid < 128) {   // h_1023 lives in hA[0]; last bar already done
    bf16x4 hv4 = *(const bf16x4*)(hA[0] + prd_off);
    float s = bf2f((unsigned short)hv4[0]) * wv[0] + bf2f((unsigned short)hv4[1]) * wv[1]
            + bf2f((unsigned short)hv4[2]) * wv[2] + bf2f((unsigned short)hv4[3]) * wv[3];
#pragma unroll
    for (int off = 16; off > 0; off >>= 1) s += __shfl_xor(s, off, 32);
    if ((tid & 31) == 0) outp[(size_t)(bg0 + pbl) * TT + (TT - 1)] = fmaxf(s + ob, 0.f);
  }
}

// ---------------- launch ----------------
extern "C" void kernel_launch(void* const* d_in, const int* in_sizes, int n_in,
                              void* d_out, int out_size, void* d_ws, size_t ws_size,
                              hipStream_t stream) {
  const float* x  = (const float*)d_in[0];
  const float* h0 = (const float*)d_in[1];
  const float* c0 = (const float*)d_in[2];
  const float* Wih[3] = {(const float*)d_in[3], (const float*)d_in[7],  (const float*)d_in[11]};
  const float* Whh[3] = {(const float*)d_in[4], (const float*)d_in[8],  (const float*)d_in[12]};
  const float* bih[3] = {(const float*)d_in[5], (const float*)d_in[9],  (const float*)d_in[13]};
  const float* bhh[3] = {(const float*)d_in[6], (const float*)d_in[10], (const float*)d_in[14]};
  const float* Wout = (const float*)d_in[15];
  const float* bout = (const float*)d_in[16];

  float* outp = (float*)d_out;                 // [B][T]
  float* hN = outp + BATCH * TT;               // [L][B][H]
  float* cN = hN + 3 * BATCH * HH;

  char* ws = (char*)d_ws;
  unsigned short* x_bf = (unsigned short*)ws;                      // 16 MB
  unsigned short* y_bf = (unsigned short*)(ws + (size_t)16777216); // 32 MB
  unsigned short* xg   = (unsigned short*)(ws + (size_t)50331648); // 128 MB

  cvt_bf16<<<8192, 256, 0, stream>>>(x, x_bf, BATCH * TT * DD);

  xg_gemm<64><<<2048, 256, 0, stream>>>(x_bf, Wih[0], bih[0], bhh[0], xg);
  lstm_rec<0><<<BATCH / NB, 512, 0, stream>>>(xg, Whh[0], h0, c0,
                                              hN, cN, y_bf, nullptr, Wout, bout);

  xg_gemm<128><<<2048, 256, 0, stream>>>(y_bf, Wih[1], bih[1], bhh[1], xg);
  lstm_rec<0><<<BATCH / NB, 512, 0, stream>>>(xg, Whh[1], h0 + BATCH * HH, c0 + BATCH * HH,
                                              hN + BATCH * HH, cN + BATCH * HH, y_bf, nullptr, Wout, bout);

  xg_gemm<128><<<2048, 256, 0, stream>>>(y_bf, Wih[2], bih[2], bhh[2], xg);
  lstm_rec<1><<<BATCH / NB, 512, 0, stream>>>(xg, Whh[2], h0 + 2 * BATCH * HH, c0 + 2 * BATCH * HH,
                                              hN + 2 * BATCH * HH, cN + 2 * BATCH * HH, nullptr, outp, Wout, bout);
}